// Round 4
// baseline (481.719 us; speedup 1.0000x reference)
//
#include <hip/hip_runtime.h>

// BlockResMLP MixerBlock: 2 layers of 64 independent block MLPs (64->128->64, ELU, residual)
// with a per-row 64x64 transpose (shuffle) around layer 2.
// bf16 MFMA (16x16x32 only), fp32 accumulate. 3 kernels:
//   k0: weight convert+transpose. w2t pi32-permuted for ALL layers; w1t pi32 for layer 1.
//   k1: layer-1 facto, pure-register (no LDS): h-transpose + x-residual via perm-B MFMAs.
//       Writes y1 in granule-16 layout [row>>4][n][m][row&15].
//   k2: layer-2 facto + inverse shuffle + fp32 out. 1024-thread WG, wave-per-m over 64 rows:
//       za prefetched for all 4 granules, weights reused across granules, double-buffered
//       out staging, 1 barrier per granule. 2 WG/CU exactly; VGPR<=128 -> 16 waves/CU.

typedef short short8 __attribute__((ext_vector_type(8)));
typedef short short4v __attribute__((ext_vector_type(4)));
typedef float floatx4 __attribute__((ext_vector_type(4)));
typedef unsigned int uintx4 __attribute__((ext_vector_type(4)));

#define MFMA(A, B, C) __builtin_amdgcn_mfma_f32_16x16x32_bf16((A), (B), (C), 0, 0, 0)

__device__ __forceinline__ unsigned short bf16r(float f) {
  unsigned int u = __builtin_bit_cast(unsigned int, f);
  u += 0x7FFFu + ((u >> 16) & 1u);   // round-to-nearest-even
  return (unsigned short)(u >> 16);
}
__device__ __forceinline__ float bf16f(unsigned short h) {
  unsigned int u = ((unsigned int)h) << 16;
  return __builtin_bit_cast(float, u);
}
__device__ __forceinline__ unsigned int pk2(float lo, float hi) {
  return (unsigned int)bf16r(lo) | ((unsigned int)bf16r(hi) << 16);
}
__device__ __forceinline__ float eluf(float v) {
  return v > 0.f ? v : (__expf(v) - 1.f);
}
__device__ __forceinline__ uint4 gather44(const short* A, const short* B, int s) {
  uint4 o;
  o.x = (unsigned int)(unsigned short)A[0 * s] |
        ((unsigned int)(unsigned short)A[1 * s] << 16);
  o.y = (unsigned int)(unsigned short)A[2 * s] |
        ((unsigned int)(unsigned short)A[3 * s] << 16);
  o.z = (unsigned int)(unsigned short)B[0 * s] |
        ((unsigned int)(unsigned short)B[1 * s] << 16);
  o.w = (unsigned int)(unsigned short)B[2 * s] |
        ((unsigned int)(unsigned short)B[3 * s] << 16);
  return o;
}

// ---------------- K0: weight prep (LDS transpose) ----------------
// w1 fp32 [l][n][d][e] (2,64,64,128)  -> w1t bf16 [l*64+n][e][d-slot]
// w2 fp32 [l][n][e][d'] (2,64,128,64) -> w2t bf16 [l*64+n][d'][e-slot]
// pi32 k-slot permutation within each 32-block:
//   slot c holds k = (c&~31) + ( (c&7)<4 ? 4*((c>>3)&3)+(c&7) : 16+4*((c>>3)&3)+(c&7)-4 )
// Applied to: w1t for ln>=64 (layer-1 GEMM1, transposed-z A-frags);
//             w2t for ALL ln  (both layers' GEMM2 consume register-transposed h).
__global__ __launch_bounds__(256) void k0_prep(const float* __restrict__ w1,
                                               const float* __restrict__ w2,
                                               short* __restrict__ w1t,
                                               short* __restrict__ w2t) {
  __shared__ __align__(16) short T[128 * 72];   // phase A uses [64][136] = 8704 shorts
  const int t  = threadIdx.x;
  const int ln = blockIdx.x >> 1;
  if ((blockIdx.x & 1) == 0) {
    // ---- w1 [64 d][128 e] -> w1t [e][d-slot] ----
    const bool pm = (ln >= 64);
    const float* src = w1 + (size_t)ln * 8192 + t * 32;
    const int d = t >> 2, e0 = (t & 3) * 32;
#pragma unroll
    for (int u = 0; u < 32; u += 2) {
      *(unsigned int*)&T[d * 136 + e0 + u] = pk2(src[u], src[u + 1]);
    }
    __syncthreads();
    const int e = t >> 1, d0 = (t & 1) * 32;
    short* dst = w1t + (size_t)ln * 8192 + e * 64 + d0;
#pragma unroll
    for (int k = 0; k < 4; ++k) {
      const int ta = d0 + (pm ? 4 * k : 8 * k);
      const int tb = d0 + (pm ? 16 + 4 * k : 8 * k + 4);
      *(uint4*)(dst + k * 8) = gather44(&T[ta * 136 + e], &T[tb * 136 + e], 136);
    }
  } else {
    // ---- w2 [128 e][64 d'] -> w2t [d'][e-slot], pi32 for all ln ----
    const float* src = w2 + (size_t)ln * 8192 + t * 32;
    const int e = t >> 1, d0 = (t & 1) * 32;
#pragma unroll
    for (int u = 0; u < 32; u += 2) {
      *(unsigned int*)&T[e * 72 + d0 + u] = pk2(src[u], src[u + 1]);
    }
    __syncthreads();
    const int dp = t >> 2, e0 = (t & 3) * 32;
    short* dst = w2t + (size_t)ln * 8192 + dp * 128 + e0;
#pragma unroll
    for (int k = 0; k < 4; ++k) {
      const int ta = e0 + 4 * k;
      const int tb = e0 + 16 + 4 * k;
      *(uint4*)(dst + k * 8) = gather44(&T[ta * 72 + dp], &T[tb * 72 + dp], 72);
    }
  }
}

// ---------------- K1: layer 0 facto, pure-register ----------------
// WG = (n-pair x 64 rows), 4 waves. No LDS, no barriers.
// h-transpose via 4-slot perm-B MFMA (pi32 w2t); residual via full-slot perm-B MFMA
// on the A-frags (x already in registers, bf16). y1: [row>>4][n][j][row&15].
__global__ __launch_bounds__(256) void k1_layer0(
    const float* __restrict__ x,
    const short* __restrict__ w1t, const short* __restrict__ w2t,
    const float* __restrict__ b1,  const float* __restrict__ b2,
    short* __restrict__ y1) {
  const int tid  = threadIdx.x;
  const int lane = tid & 63;
  const int wv   = tid >> 6;
  const int il   = lane & 15;
  const int q    = lane >> 4;
  const int npair   = blockIdx.x & 31;
  const int rowtile = blockIdx.x >> 5;
  const int n  = npair * 2 + (wv & 1);
  const int r0 = rowtile * 64 + (wv >> 1) * 32;     // 32-row aligned

  const short* w1n = w1t + (size_t)n * 8192;
  const short* w2n = w2t + (size_t)n * 8192;
  const float* b1n = b1 + n * 128;
  const float* b2n = b2 + n * 64;

  const floatx4 zero4 = {0.f, 0.f, 0.f, 0.f};
  // 4-slot transpose perm: B[k][n] nonzero at k = (n>>2)*8 + (n&3) (slots 0..3 of A)
  short8 pbH;
#pragma unroll
  for (int v = 0; v < 8; ++v) pbH[v] = (v < 4 && il == q * 4 + v) ? (short)0x3F80 : (short)0;

  // hoisted A-frags: load + convert x once
  short8 a[2][2];   // [ks][Mt]
#pragma unroll
  for (int Mt = 0; Mt < 2; ++Mt) {
#pragma unroll
    for (int ks = 0; ks < 2; ++ks) {
      const float* xp = x + (size_t)(r0 + Mt * 16 + il) * 4096 + n * 64 + ks * 32 + q * 8;
      floatx4 f0 = *(const floatx4*)xp;
      floatx4 f1 = *(const floatx4*)(xp + 4);
      short8 t;
#pragma unroll
      for (int u = 0; u < 4; ++u) { t[u] = (short)bf16r(f0[u]); t[4 + u] = (short)bf16r(f1[u]); }
      a[ks][Mt] = t;
    }
  }

  floatx4 acc2[2][4] = {};
  for (int hh = 0; hh < 2; ++hh) {
    floatx4 acc1[2][4] = {};
#pragma unroll
    for (int ks = 0; ks < 2; ++ks) {
#pragma unroll
      for (int nt = 0; nt < 4; ++nt) {
        short8 b = *(const short8*)(w1n + (hh * 64 + nt * 16 + il) * 64 + ks * 32 + q * 8);
        acc1[0][nt] = MFMA(a[ks][0], b, acc1[0][nt]);
        acc1[1][nt] = MFMA(a[ks][1], b, acc1[1][nt]);
      }
    }
    // bias + ELU -> bf16 -> h-transpose via perm-B MFMA -> GEMM2 A-frags (pi32 order)
    uintx4 a2w[2][2];   // [Mt][ks2l]
#pragma unroll
    for (int Mt = 0; Mt < 2; ++Mt) {
#pragma unroll
      for (int nt = 0; nt < 4; ++nt) {
        const float bias = b1n[hh * 64 + nt * 16 + il];
        short8 ha = {(short)bf16r(eluf(acc1[Mt][nt][0] + bias)),
                     (short)bf16r(eluf(acc1[Mt][nt][1] + bias)),
                     (short)bf16r(eluf(acc1[Mt][nt][2] + bias)),
                     (short)bf16r(eluf(acc1[Mt][nt][3] + bias)),
                     0, 0, 0, 0};
        floatx4 hd = MFMA(ha, pbH, zero4);
        // hd: lane holds h(r = r0+Mt*16+il, e = hh*64 + nt*16 + q*4+rg)
        const int ks2l = nt >> 1;
        const int hf   = nt & 1;
        a2w[Mt][ks2l][hf * 2 + 0] = pk2(hd[0], hd[1]);
        a2w[Mt][ks2l][hf * 2 + 1] = pk2(hd[2], hd[3]);
      }
    }
#pragma unroll
    for (int ks2l = 0; ks2l < 2; ++ks2l) {
      short8 af0 = __builtin_bit_cast(short8, a2w[0][ks2l]);
      short8 af1 = __builtin_bit_cast(short8, a2w[1][ks2l]);
#pragma unroll
      for (int nt2 = 0; nt2 < 4; ++nt2) {
        short8 b = *(const short8*)(w2n + (nt2 * 16 + il) * 128 + hh * 64 + ks2l * 32 + q * 8);
        acc2[0][nt2] = MFMA(af0, b, acc2[0][nt2]);
        acc2[1][nt2] = MFMA(af1, b, acc2[1][nt2]);
      }
    }
  }

  // full-slot residual perms: pb0: B[k][n]=d(k==n); pb1: B[k][n]=d(k==n+16)
  short8 pb0, pb1;
#pragma unroll
  for (int v = 0; v < 8; ++v) {
    pb0[v] = (q * 8 + v == il)      ? (short)0x3F80 : (short)0;
    pb1[v] = (q * 8 + v == il + 16) ? (short)0x3F80 : (short)0;
  }
  // epilogue: bias + bf16(x) residual from A-frag transpose; coalesced 512B-run stores
#pragma unroll
  for (int Mt = 0; Mt < 2; ++Mt) {
    const size_t nbase = ((size_t)((r0 + Mt * 16) >> 4) * 64 + n) * 64;
#pragma unroll
    for (int ks = 0; ks < 2; ++ks) {
      floatx4 xr[2];
      xr[0] = MFMA(a[ks][Mt], pb0, zero4);   // x(row=r0+Mt*16+q*4+rg, d=ks*32+il)
      xr[1] = MFMA(a[ks][Mt], pb1, zero4);   // x(row=..., d=ks*32+16+il)
#pragma unroll
      for (int h = 0; h < 2; ++h) {
        const int nt2 = ks * 2 + h;
        const int j = nt2 * 16 + il;
        const float bias = b2n[j];
        uint2 pk;
        pk.x = pk2(acc2[Mt][nt2][0] + bias + xr[h][0],
                   acc2[Mt][nt2][1] + bias + xr[h][1]);
        pk.y = pk2(acc2[Mt][nt2][2] + bias + xr[h][2],
                   acc2[Mt][nt2][3] + bias + xr[h][3]);
        *(uint2*)(y1 + (nbase + j) * 16 + q * 4) = pk;
      }
    }
  }
}

// ---------------- K2: layer 1 facto + inverse shuffle + fp32 out ----------------
// WG = 1024 threads (16 waves), wave owns ONE m over 64 rows (4 granules).
// za prefetched for all granules; weights reused across granules; per-granule
// double-buffered out staging + 1 barrier; full-64B-line fp32 stores.
#define RSTR 1156
#define ISTR 18
__global__ __launch_bounds__(1024) void k2_layer1_out(
    const short* __restrict__ y1,
    const short* __restrict__ w1t, const short* __restrict__ w2t,
    const float* __restrict__ b1,  const float* __restrict__ b2,
    float* __restrict__ out) {
  __shared__ __align__(16) short yo[2][16 * RSTR];   // 2 x 36992 B
  const int tid  = threadIdx.x;
  const int lane = tid & 63;
  const int wv   = tid >> 6;                 // 0..15 = m within window
  const int il   = lane & 15;
  const int q    = lane >> 4;
  const int rowband = blockIdx.x & 127;      // 64-row band
  const int m0      = (blockIdx.x >> 7) * 16;
  const int m       = m0 + wv;

  // 4-slot transpose perm-B
  short8 pb;
#pragma unroll
  for (int v = 0; v < 8; ++v) pb[v] = (v < 4 && il == q * 4 + v) ? (short)0x3F80 : (short)0;
  const floatx4 zero4 = {0.f, 0.f, 0.f, 0.f};

  const short* w1m = w1t + (size_t)(64 + m) * 8192;
  const short* w2m = w2t + (size_t)(64 + m) * 8192;
  const float* b1m = b1 + (64 + m) * 128;
  const float* b2m = b2 + (64 + m) * 64;

  // ---- prefetch za for all 4 granules (16 independent b64 loads) ----
  short4v za[4][4];   // [g][nt]
#pragma unroll
  for (int g = 0; g < 4; ++g) {
    const int G = rowband * 4 + g;
#pragma unroll
    for (int nt = 0; nt < 4; ++nt)
      za[g][nt] = *(const short4v*)(y1 + ((size_t)(G * 64 + nt * 16 + il) * 64 + m) * 16 + q * 4);
  }

  // flush-phase thread mapping (same every granule)
  const int fmq = tid & 3;           // m-quad
  const int fiw = (tid >> 2) & 63;   // i
  const int frr = tid >> 8;          // 0..3 (row sub)

#pragma unroll
  for (int g = 0; g < 4; ++g) {
    // ---- z-transpose via perm-B MFMA ----
    floatx4 zd[4];
#pragma unroll
    for (int nt = 0; nt < 4; ++nt) {
      short8 az = {za[g][nt][0], za[g][nt][1], za[g][nt][2], za[g][nt][3], 0, 0, 0, 0};
      zd[nt] = MFMA(az, pb, zero4);
    }
    short8 at[2];
#pragma unroll
    for (int ks = 0; ks < 2; ++ks) {
      uintx4 w;
      w[0] = pk2(zd[2 * ks][0], zd[2 * ks][1]);
      w[1] = pk2(zd[2 * ks][2], zd[2 * ks][3]);
      w[2] = pk2(zd[2 * ks + 1][0], zd[2 * ks + 1][1]);
      w[3] = pk2(zd[2 * ks + 1][2], zd[2 * ks + 1][3]);
      at[ks] = __builtin_bit_cast(short8, w);
    }

    floatx4 acc2[4] = {};
    uintx4 a2w[4];
#pragma unroll
    for (int hh = 0; hh < 2; ++hh) {
      floatx4 acc1[4] = {};
#pragma unroll
      for (int ks = 0; ks < 2; ++ks)
#pragma unroll
        for (int nt = 0; nt < 4; ++nt) {
          short8 b = *(const short8*)(w1m + (hh * 64 + nt * 16 + il) * 64 + ks * 32 + q * 8);
          acc1[nt] = MFMA(at[ks], b, acc1[nt]);
        }
#pragma unroll
      for (int nt = 0; nt < 4; ++nt) {
        const float bias = b1m[hh * 64 + nt * 16 + il];
        short8 ha = {(short)bf16r(eluf(acc1[nt][0] + bias)),
                     (short)bf16r(eluf(acc1[nt][1] + bias)),
                     (short)bf16r(eluf(acc1[nt][2] + bias)),
                     (short)bf16r(eluf(acc1[nt][3] + bias)),
                     0, 0, 0, 0};
        floatx4 hd = MFMA(ha, pb, zero4);
        const int ks2 = hh * 2 + (nt >> 1);
        const int hf  = nt & 1;
        a2w[ks2][hf * 2 + 0] = pk2(hd[0], hd[1]);
        a2w[ks2][hf * 2 + 1] = pk2(hd[2], hd[3]);
      }
    }
#pragma unroll
    for (int ks2 = 0; ks2 < 4; ++ks2) {
      short8 af = __builtin_bit_cast(short8, a2w[ks2]);
#pragma unroll
      for (int nt2 = 0; nt2 < 4; ++nt2) {
        short8 b = *(const short8*)(w2m + (nt2 * 16 + il) * 128 + ks2 * 32 + q * 8);
        acc2[nt2] = MFMA(af, b, acc2[nt2]);
      }
    }
    // epilogue: bias + residual (za regs) -> yo[g&1]
    short* yob = &yo[g & 1][0];
#pragma unroll
    for (int nt2 = 0; nt2 < 4; ++nt2) {
      const int i = nt2 * 16 + il;
      const float bias = b2m[i];
#pragma unroll
      for (int rg = 0; rg < 4; ++rg) {
        float val = acc2[nt2][rg] + bias + bf16f((unsigned short)za[g][nt2][rg]);
        yob[(q * 4 + rg) * RSTR + i * ISTR + wv] = (short)bf16r(val);
      }
    }
    __syncthreads();
    // ---- flush granule g: out[G*16+r][iw*64 + m0 + fmq*4 .. +3], full 64B lines ----
    {
      const int G = rowband * 4 + g;
#pragma unroll
      for (int p = 0; p < 4; ++p) {
        const int r = p * 4 + frr;
        const short* yr = &yo[g & 1][r * RSTR + fiw * ISTR + fmq * 4];
        unsigned int w0 = *(const unsigned int*)(yr);
        unsigned int w1_ = *(const unsigned int*)(yr + 2);
        floatx4 vv = {bf16f((unsigned short)(w0 & 0xffffu)),
                      bf16f((unsigned short)(w0 >> 16)),
                      bf16f((unsigned short)(w1_ & 0xffffu)),
                      bf16f((unsigned short)(w1_ >> 16))};
        *(floatx4*)(out + (size_t)(G * 16 + r) * 4096 + fiw * 64 + m0 + fmq * 4) = vv;
      }
    }
    // next granule writes the other yo buffer; the following iteration's barrier
    // separates these flush reads from the epilogue that overwrites this buffer.
  }
}

extern "C" void kernel_launch(void* const* d_in, const int* in_sizes, int n_in,
                              void* d_out, int out_size, void* d_ws, size_t ws_size,
                              hipStream_t stream) {
  const float* x  = (const float*)d_in[0];
  const float* w1 = (const float*)d_in[1];
  const float* b1 = (const float*)d_in[2];
  const float* w2 = (const float*)d_in[3];
  const float* b2 = (const float*)d_in[4];
  float* out = (float*)d_out;

  short* w1t = (short*)d_ws;
  short* w2t = w1t + (1u << 20);
  short* y1  = w2t + (1u << 20);

  hipLaunchKernelGGL(k0_prep,       dim3(256),  dim3(256),  0, stream, w1, w2, w1t, w2t);
  hipLaunchKernelGGL(k1_layer0,     dim3(4096), dim3(256),  0, stream, x, w1t, w2t, b1, b2, y1);
  hipLaunchKernelGGL(k2_layer1_out, dim3(512),  dim3(1024), 0, stream, y1, w1t, w2t, b1, b2, out);
}

// Round 5
// 451.788 us; speedup vs baseline: 1.0663x; 1.0663x over previous
//
#include <hip/hip_runtime.h>

// BlockResMLP MixerBlock: 2 layers of 64 independent block MLPs (64->128->64, ELU, residual)
// with a per-row 64x64 transpose (shuffle) around layer 2.
// bf16 MFMA (16x16x32 only), fp32 accumulate. 3 kernels:
//   k0: weight convert+transpose. w2t pi32-permuted for ALL layers; w1t pi32 for layer 1.
//   k1: layer-1 facto, pure-register (no LDS): h-transpose + x-residual via perm-B MFMAs.
//       Writes y1 in granule-16 layout [row>>4][n][m][row&15].
//   k2: layer-2 facto + inverse shuffle + fp32 out. WG = one 16-row granule x ALL 64 m's
//       (16 waves, wave owns 4 m's in two phases). Flush writes FULL 128-B out lines from
//       one WG only -> no cross-XCD partial-line RMW (round-4 regression fix).

typedef short short8 __attribute__((ext_vector_type(8)));
typedef short short4v __attribute__((ext_vector_type(4)));
typedef float floatx4 __attribute__((ext_vector_type(4)));
typedef unsigned int uintx4 __attribute__((ext_vector_type(4)));

#define MFMA(A, B, C) __builtin_amdgcn_mfma_f32_16x16x32_bf16((A), (B), (C), 0, 0, 0)

__device__ __forceinline__ unsigned short bf16r(float f) {
  unsigned int u = __builtin_bit_cast(unsigned int, f);
  u += 0x7FFFu + ((u >> 16) & 1u);   // round-to-nearest-even
  return (unsigned short)(u >> 16);
}
__device__ __forceinline__ float bf16f(unsigned short h) {
  unsigned int u = ((unsigned int)h) << 16;
  return __builtin_bit_cast(float, u);
}
__device__ __forceinline__ unsigned int pk2(float lo, float hi) {
  return (unsigned int)bf16r(lo) | ((unsigned int)bf16r(hi) << 16);
}
__device__ __forceinline__ float eluf(float v) {
  return v > 0.f ? v : (__expf(v) - 1.f);
}
__device__ __forceinline__ uint4 gather44(const short* A, const short* B, int s) {
  uint4 o;
  o.x = (unsigned int)(unsigned short)A[0 * s] |
        ((unsigned int)(unsigned short)A[1 * s] << 16);
  o.y = (unsigned int)(unsigned short)A[2 * s] |
        ((unsigned int)(unsigned short)A[3 * s] << 16);
  o.z = (unsigned int)(unsigned short)B[0 * s] |
        ((unsigned int)(unsigned short)B[1 * s] << 16);
  o.w = (unsigned int)(unsigned short)B[2 * s] |
        ((unsigned int)(unsigned short)B[3 * s] << 16);
  return o;
}

// ---------------- K0: weight prep (LDS transpose) ----------------
// w1 fp32 [l][n][d][e] (2,64,64,128)  -> w1t bf16 [l*64+n][e][d-slot]
// w2 fp32 [l][n][e][d'] (2,64,128,64) -> w2t bf16 [l*64+n][d'][e-slot]
// pi32 k-slot permutation within each 32-block:
//   slot c holds k = (c&~31) + ( (c&7)<4 ? 4*((c>>3)&3)+(c&7) : 16+4*((c>>3)&3)+(c&7)-4 )
// Applied to: w1t for ln>=64 (layer-1 GEMM1, transposed-z A-frags);
//             w2t for ALL ln  (both layers' GEMM2 consume register-transposed h).
__global__ __launch_bounds__(256) void k0_prep(const float* __restrict__ w1,
                                               const float* __restrict__ w2,
                                               short* __restrict__ w1t,
                                               short* __restrict__ w2t) {
  __shared__ __align__(16) short T[128 * 72];   // phase A uses [64][136] = 8704 shorts
  const int t  = threadIdx.x;
  const int ln = blockIdx.x >> 1;
  if ((blockIdx.x & 1) == 0) {
    // ---- w1 [64 d][128 e] -> w1t [e][d-slot] ----
    const bool pm = (ln >= 64);
    const float* src = w1 + (size_t)ln * 8192 + t * 32;
    const int d = t >> 2, e0 = (t & 3) * 32;
#pragma unroll
    for (int u = 0; u < 32; u += 2) {
      *(unsigned int*)&T[d * 136 + e0 + u] = pk2(src[u], src[u + 1]);
    }
    __syncthreads();
    const int e = t >> 1, d0 = (t & 1) * 32;
    short* dst = w1t + (size_t)ln * 8192 + e * 64 + d0;
#pragma unroll
    for (int k = 0; k < 4; ++k) {
      const int ta = d0 + (pm ? 4 * k : 8 * k);
      const int tb = d0 + (pm ? 16 + 4 * k : 8 * k + 4);
      *(uint4*)(dst + k * 8) = gather44(&T[ta * 136 + e], &T[tb * 136 + e], 136);
    }
  } else {
    // ---- w2 [128 e][64 d'] -> w2t [d'][e-slot], pi32 for all ln ----
    const float* src = w2 + (size_t)ln * 8192 + t * 32;
    const int e = t >> 1, d0 = (t & 1) * 32;
#pragma unroll
    for (int u = 0; u < 32; u += 2) {
      *(unsigned int*)&T[e * 72 + d0 + u] = pk2(src[u], src[u + 1]);
    }
    __syncthreads();
    const int dp = t >> 2, e0 = (t & 3) * 32;
    short* dst = w2t + (size_t)ln * 8192 + dp * 128 + e0;
#pragma unroll
    for (int k = 0; k < 4; ++k) {
      const int ta = e0 + 4 * k;
      const int tb = e0 + 16 + 4 * k;
      *(uint4*)(dst + k * 8) = gather44(&T[ta * 72 + dp], &T[tb * 72 + dp], 72);
    }
  }
}

// ---------------- K1: layer 0 facto, pure-register (unchanged, verified) ----------------
// WG = (n-pair x 64 rows), 4 waves. No LDS, no barriers.
// h-transpose via 4-slot perm-B MFMA (pi32 w2t); residual via full-slot perm-B MFMA
// on the A-frags (x already in registers, bf16). y1: [row>>4][n][j][row&15].
__global__ __launch_bounds__(256) void k1_layer0(
    const float* __restrict__ x,
    const short* __restrict__ w1t, const short* __restrict__ w2t,
    const float* __restrict__ b1,  const float* __restrict__ b2,
    short* __restrict__ y1) {
  const int tid  = threadIdx.x;
  const int lane = tid & 63;
  const int wv   = tid >> 6;
  const int il   = lane & 15;
  const int q    = lane >> 4;
  const int npair   = blockIdx.x & 31;
  const int rowtile = blockIdx.x >> 5;
  const int n  = npair * 2 + (wv & 1);
  const int r0 = rowtile * 64 + (wv >> 1) * 32;     // 32-row aligned

  const short* w1n = w1t + (size_t)n * 8192;
  const short* w2n = w2t + (size_t)n * 8192;
  const float* b1n = b1 + n * 128;
  const float* b2n = b2 + n * 64;

  const floatx4 zero4 = {0.f, 0.f, 0.f, 0.f};
  // 4-slot transpose perm: B[k][n] nonzero at k = (n>>2)*8 + (n&3) (slots 0..3 of A)
  short8 pbH;
#pragma unroll
  for (int v = 0; v < 8; ++v) pbH[v] = (v < 4 && il == q * 4 + v) ? (short)0x3F80 : (short)0;

  // hoisted A-frags: load + convert x once
  short8 a[2][2];   // [ks][Mt]
#pragma unroll
  for (int Mt = 0; Mt < 2; ++Mt) {
#pragma unroll
    for (int ks = 0; ks < 2; ++ks) {
      const float* xp = x + (size_t)(r0 + Mt * 16 + il) * 4096 + n * 64 + ks * 32 + q * 8;
      floatx4 f0 = *(const floatx4*)xp;
      floatx4 f1 = *(const floatx4*)(xp + 4);
      short8 t;
#pragma unroll
      for (int u = 0; u < 4; ++u) { t[u] = (short)bf16r(f0[u]); t[4 + u] = (short)bf16r(f1[u]); }
      a[ks][Mt] = t;
    }
  }

  floatx4 acc2[2][4] = {};
  for (int hh = 0; hh < 2; ++hh) {
    floatx4 acc1[2][4] = {};
#pragma unroll
    for (int ks = 0; ks < 2; ++ks) {
#pragma unroll
      for (int nt = 0; nt < 4; ++nt) {
        short8 b = *(const short8*)(w1n + (hh * 64 + nt * 16 + il) * 64 + ks * 32 + q * 8);
        acc1[0][nt] = MFMA(a[ks][0], b, acc1[0][nt]);
        acc1[1][nt] = MFMA(a[ks][1], b, acc1[1][nt]);
      }
    }
    // bias + ELU -> bf16 -> h-transpose via perm-B MFMA -> GEMM2 A-frags (pi32 order)
    uintx4 a2w[2][2];   // [Mt][ks2l]
#pragma unroll
    for (int Mt = 0; Mt < 2; ++Mt) {
#pragma unroll
      for (int nt = 0; nt < 4; ++nt) {
        const float bias = b1n[hh * 64 + nt * 16 + il];
        short8 ha = {(short)bf16r(eluf(acc1[Mt][nt][0] + bias)),
                     (short)bf16r(eluf(acc1[Mt][nt][1] + bias)),
                     (short)bf16r(eluf(acc1[Mt][nt][2] + bias)),
                     (short)bf16r(eluf(acc1[Mt][nt][3] + bias)),
                     0, 0, 0, 0};
        floatx4 hd = MFMA(ha, pbH, zero4);
        // hd: lane holds h(r = r0+Mt*16+il, e = hh*64 + nt*16 + q*4+rg)
        const int ks2l = nt >> 1;
        const int hf   = nt & 1;
        a2w[Mt][ks2l][hf * 2 + 0] = pk2(hd[0], hd[1]);
        a2w[Mt][ks2l][hf * 2 + 1] = pk2(hd[2], hd[3]);
      }
    }
#pragma unroll
    for (int ks2l = 0; ks2l < 2; ++ks2l) {
      short8 af0 = __builtin_bit_cast(short8, a2w[0][ks2l]);
      short8 af1 = __builtin_bit_cast(short8, a2w[1][ks2l]);
#pragma unroll
      for (int nt2 = 0; nt2 < 4; ++nt2) {
        short8 b = *(const short8*)(w2n + (nt2 * 16 + il) * 128 + hh * 64 + ks2l * 32 + q * 8);
        acc2[0][nt2] = MFMA(af0, b, acc2[0][nt2]);
        acc2[1][nt2] = MFMA(af1, b, acc2[1][nt2]);
      }
    }
  }

  // full-slot residual perms: pb0: B[k][n]=d(k==n); pb1: B[k][n]=d(k==n+16)
  short8 pb0, pb1;
#pragma unroll
  for (int v = 0; v < 8; ++v) {
    pb0[v] = (q * 8 + v == il)      ? (short)0x3F80 : (short)0;
    pb1[v] = (q * 8 + v == il + 16) ? (short)0x3F80 : (short)0;
  }
  // epilogue: bias + bf16(x) residual from A-frag transpose; coalesced 512B-run stores
#pragma unroll
  for (int Mt = 0; Mt < 2; ++Mt) {
    const size_t nbase = ((size_t)((r0 + Mt * 16) >> 4) * 64 + n) * 64;
#pragma unroll
    for (int ks = 0; ks < 2; ++ks) {
      floatx4 xr[2];
      xr[0] = MFMA(a[ks][Mt], pb0, zero4);   // x(row=r0+Mt*16+q*4+rg, d=ks*32+il)
      xr[1] = MFMA(a[ks][Mt], pb1, zero4);   // x(row=..., d=ks*32+16+il)
#pragma unroll
      for (int h = 0; h < 2; ++h) {
        const int nt2 = ks * 2 + h;
        const int j = nt2 * 16 + il;
        const float bias = b2n[j];
        uint2 pk;
        pk.x = pk2(acc2[Mt][nt2][0] + bias + xr[h][0],
                   acc2[Mt][nt2][1] + bias + xr[h][1]);
        pk.y = pk2(acc2[Mt][nt2][2] + bias + xr[h][2],
                   acc2[Mt][nt2][3] + bias + xr[h][3]);
        *(uint2*)(y1 + (nbase + j) * 16 + q * 4) = pk;
      }
    }
  }
}

// ---------------- K2: layer 1 facto + inverse shuffle + fp32 out ----------------
// WG = one 16-row granule x ALL 64 m's. 16 waves; wave wv owns m in
// {2wv, 2wv+1, 32+2wv, 32+2wv+1} (two phases of the m-halves). za prefetched for all
// 4 m's up front. Per phase: compute 2 m's -> stage yo[r][i][ml] -> barrier ->
// flush full 128-B out lines (8-lane clusters) -> barrier.
#define RSTR 2308   // r-stride (shorts): 64*36 + 4 -> q spreads banks
#define ISTR 36     // i-stride (shorts): 72 B, 8-B aligned b64 reads, gcd(18,32)=2
__global__ __launch_bounds__(1024) void k2_layer1_out(
    const short* __restrict__ y1,
    const short* __restrict__ w1t, const short* __restrict__ w2t,
    const float* __restrict__ b1,  const float* __restrict__ b2,
    float* __restrict__ out) {
  __shared__ __align__(16) short yo[16 * RSTR];   // 73856 B
  const int tid  = threadIdx.x;
  const int lane = tid & 63;
  const int wv   = tid >> 6;                 // 0..15
  const int il   = lane & 15;
  const int q    = lane >> 4;
  const int G    = blockIdx.x;               // granule (16 rows)

  // 4-slot transpose perm-B
  short8 pb;
#pragma unroll
  for (int v = 0; v < 8; ++v) pb[v] = (v < 4 && il == q * 4 + v) ? (short)0x3F80 : (short)0;
  const floatx4 zero4 = {0.f, 0.f, 0.f, 0.f};

  // ---- prefetch za for all 4 m's (16 independent b64 loads, one latency) ----
  short4v za[2][2][4];   // [p][mi][nt]
#pragma unroll
  for (int p = 0; p < 2; ++p)
#pragma unroll
    for (int mi = 0; mi < 2; ++mi) {
      const int m = p * 32 + wv * 2 + mi;
#pragma unroll
      for (int nt = 0; nt < 4; ++nt)
        za[p][mi][nt] =
            *(const short4v*)(y1 + ((size_t)(G * 64 + nt * 16 + il) * 64 + m) * 16 + q * 4);
    }

  // flush mapping: 8-lane clusters each own one (r,i) 128-B half-segment
  const int fsub = tid & 7;          // 16-B unit within the 128-B line
  const int fic  = (tid >> 3) & 7;   // i-cluster
  const int fr   = tid >> 6;         // row (== wv)

#pragma unroll
  for (int p = 0; p < 2; ++p) {
#pragma unroll
    for (int mi = 0; mi < 2; ++mi) {
      const int ml = wv * 2 + mi;
      const int m  = p * 32 + ml;
      const short* w1m = w1t + (size_t)(64 + m) * 8192;
      const short* w2m = w2t + (size_t)(64 + m) * 8192;
      const float* b1m = b1 + (64 + m) * 128;
      const float* b2m = b2 + (64 + m) * 64;

      // ---- z-transpose via perm-B MFMA ----
      floatx4 zd[4];
#pragma unroll
      for (int nt = 0; nt < 4; ++nt) {
        short8 az = {za[p][mi][nt][0], za[p][mi][nt][1], za[p][mi][nt][2], za[p][mi][nt][3],
                     0, 0, 0, 0};
        zd[nt] = MFMA(az, pb, zero4);
      }
      short8 at[2];
#pragma unroll
      for (int ks = 0; ks < 2; ++ks) {
        uintx4 w;
        w[0] = pk2(zd[2 * ks][0], zd[2 * ks][1]);
        w[1] = pk2(zd[2 * ks][2], zd[2 * ks][3]);
        w[2] = pk2(zd[2 * ks + 1][0], zd[2 * ks + 1][1]);
        w[3] = pk2(zd[2 * ks + 1][2], zd[2 * ks + 1][3]);
        at[ks] = __builtin_bit_cast(short8, w);
      }

      floatx4 acc2[4] = {};
      uintx4 a2w[4];
#pragma unroll
      for (int hh = 0; hh < 2; ++hh) {
        floatx4 acc1[4] = {};
#pragma unroll
        for (int ks = 0; ks < 2; ++ks)
#pragma unroll
          for (int nt = 0; nt < 4; ++nt) {
            short8 b = *(const short8*)(w1m + (hh * 64 + nt * 16 + il) * 64 + ks * 32 + q * 8);
            acc1[nt] = MFMA(at[ks], b, acc1[nt]);
          }
#pragma unroll
        for (int nt = 0; nt < 4; ++nt) {
          const float bias = b1m[hh * 64 + nt * 16 + il];
          short8 ha = {(short)bf16r(eluf(acc1[nt][0] + bias)),
                       (short)bf16r(eluf(acc1[nt][1] + bias)),
                       (short)bf16r(eluf(acc1[nt][2] + bias)),
                       (short)bf16r(eluf(acc1[nt][3] + bias)),
                       0, 0, 0, 0};
          floatx4 hd = MFMA(ha, pb, zero4);
          const int ks2 = hh * 2 + (nt >> 1);
          const int hf  = nt & 1;
          a2w[ks2][hf * 2 + 0] = pk2(hd[0], hd[1]);
          a2w[ks2][hf * 2 + 1] = pk2(hd[2], hd[3]);
        }
      }
#pragma unroll
      for (int ks2 = 0; ks2 < 4; ++ks2) {
        short8 af = __builtin_bit_cast(short8, a2w[ks2]);
#pragma unroll
        for (int nt2 = 0; nt2 < 4; ++nt2) {
          short8 b = *(const short8*)(w2m + (nt2 * 16 + il) * 128 + ks2 * 32 + q * 8);
          acc2[nt2] = MFMA(af, b, acc2[nt2]);
        }
      }
      // epilogue: bias + residual (za regs) -> yo[r][i][ml]
#pragma unroll
      for (int nt2 = 0; nt2 < 4; ++nt2) {
        const int i = nt2 * 16 + il;
        const float bias = b2m[i];
#pragma unroll
        for (int rg = 0; rg < 4; ++rg) {
          float val = acc2[nt2][rg] + bias + bf16f((unsigned short)za[p][mi][nt2][rg]);
          yo[(q * 4 + rg) * RSTR + i * ISTR + ml] = (short)bf16r(val);
        }
      }
    }
    __syncthreads();
    // ---- flush phase p: out[G*16+r][i*64 + p*32 + ml], full 128-B lines ----
#pragma unroll
    for (int k = 0; k < 8; ++k) {
      const int i = fic * 8 + k;
      const short* yr = &yo[fr * RSTR + i * ISTR + fsub * 4];
      uint2 w = *(const uint2*)yr;   // 8-B aligned
      floatx4 vv = {bf16f((unsigned short)(w.x & 0xffffu)),
                    bf16f((unsigned short)(w.x >> 16)),
                    bf16f((unsigned short)(w.y & 0xffffu)),
                    bf16f((unsigned short)(w.y >> 16))};
      *(floatx4*)(out + (size_t)(G * 16 + fr) * 4096 + i * 64 + p * 32 + fsub * 4) = vv;
    }
    __syncthreads();
  }
}

extern "C" void kernel_launch(void* const* d_in, const int* in_sizes, int n_in,
                              void* d_out, int out_size, void* d_ws, size_t ws_size,
                              hipStream_t stream) {
  const float* x  = (const float*)d_in[0];
  const float* w1 = (const float*)d_in[1];
  const float* b1 = (const float*)d_in[2];
  const float* w2 = (const float*)d_in[3];
  const float* b2 = (const float*)d_in[4];
  float* out = (float*)d_out;

  short* w1t = (short*)d_ws;
  short* w2t = w1t + (1u << 20);
  short* y1  = w2t + (1u << 20);

  hipLaunchKernelGGL(k0_prep,       dim3(256),  dim3(256),  0, stream, w1, w2, w1t, w2t);
  hipLaunchKernelGGL(k1_layer0,     dim3(4096), dim3(256),  0, stream, x, w1t, w2t, b1, b2, y1);
  hipLaunchKernelGGL(k2_layer1_out, dim3(512),  dim3(1024), 0, stream, y1, w1t, w2t, b1, b2, out);
}